// Round 5
// baseline (759.047 us; speedup 1.0000x reference)
//
#include <hip/hip_runtime.h>
#include <hip/hip_bf16.h>

#define BB 512      // batch
#define DD 2048     // input dim
#define KK 4096     // code dim
#define CC 512      // cause dim
#define LR 0.001f
#define GAMMA 0.1f

typedef __attribute__((ext_vector_type(8))) short short8;
typedef __attribute__((ext_vector_type(4))) float f32x4;

__device__ __forceinline__ unsigned short f2bf(float f) {
  union { float f; unsigned u; } x; x.f = f;
  unsigned r = x.u + 0x7FFF + ((x.u >> 16) & 1);   // RNE
  return (unsigned short)(r >> 16);
}

__device__ __forceinline__ void g2l16(const void* g, void* l) {
  __builtin_amdgcn_global_load_lds(
      (const __attribute__((address_space(1))) void*)g,
      (__attribute__((address_space(3))) void*)l, 16, 0, 0);
}

__device__ __forceinline__ void store4bf(unsigned short* p, f32x4 v) {
  const unsigned lo = (unsigned)f2bf(v[0]) | ((unsigned)f2bf(v[1]) << 16);
  const unsigned hi = (unsigned)f2bf(v[2]) | ((unsigned)f2bf(v[3]) << 16);
  *(uint2*)p = uint2{lo, hi};
}

// bijective XCD-chunked swizzle (T1): XCD c gets bn-chunk of gx/8 columns,
// all bm rows -> per-XCD L2 working set = its B chunk + all A panels.
__device__ __forceinline__ void xcd_swz(int gx, int& bx, int& by) {
  if ((gx & 7) == 0) {
    const int lin = by * gx + bx;
    const int c = lin & 7, j = lin >> 3;
    const int P = gx >> 3;
    bx = c * P + j % P;
    by = j / P;
  }
}

// ---------------------------------------------------------------------------
// Pipelined 64(M)x128(N) tile K-loop, BK=64. 4 waves 2x2, wave tile 32x64
// (acc 2x4, 16 MFMA/wave/iter). 3 LDS buffer sets (A 8KB + B 16KB each),
// 2 tiles staged ahead, stage issued BEFORE compute (coverage ~2 iters),
// counted vmcnt(6). XOR-swizzled LDS via pre-swizzled global source.
// Safety: stage(t+2) writes buf (t+2)%3 == (t-1)%3; barrier(t) guarantees
// all waves completed compute(t-1) (their ds_reads retired before their
// consuming MFMAs issued), so the overwrite is race-free.
// ---------------------------------------------------------------------------
__device__ __forceinline__ void mm_pipe128(
    const unsigned short* __restrict__ ag,   // lane-adjusted A base
    const unsigned short* __restrict__ bg,   // lane-adjusted B base
    int Kd, int nt,
    unsigned short* As,                      // [3][4096]
    unsigned short* Bs,                      // [3][8192]
    int lbase, int fr, int fq, int wr, int wc,
    f32x4 acc[2][4]) {
#define STAGE(ti)                                                        \
  {                                                                      \
    const int _k0 = (ti) << 6;                                           \
    unsigned short* _Ab = As + ((ti) % 3) * 4096;                        \
    unsigned short* _Bb = Bs + ((ti) % 3) * 8192;                        \
    g2l16(ag + _k0, _Ab + lbase);                                        \
    g2l16(ag + (size_t)32 * Kd + _k0, _Ab + 2048 + lbase);               \
    g2l16(bg + _k0, _Bb + lbase);                                        \
    g2l16(bg + (size_t)32 * Kd + _k0, _Bb + 2048 + lbase);               \
    g2l16(bg + (size_t)64 * Kd + _k0, _Bb + 4096 + lbase);               \
    g2l16(bg + (size_t)96 * Kd + _k0, _Bb + 6144 + lbase);               \
  }
  STAGE(0)
  STAGE(1)
  for (int t = 0; t < nt; t++) {
    if (t + 1 < nt) asm volatile("s_waitcnt vmcnt(6)" ::: "memory");
    else            asm volatile("s_waitcnt vmcnt(0)" ::: "memory");
    __builtin_amdgcn_s_barrier();
    if (t + 2 < nt) STAGE(t + 2)

    const unsigned short* Ab = As + (t % 3) * 4096;
    const unsigned short* Bb = Bs + (t % 3) * 8192;
#pragma unroll
    for (int kk = 0; kk < 2; kk++) {
      const int kx = (kk * 64 + fq * 16) ^ ((fr & 7) << 4);
      short8 af[2], bf2[4];
#pragma unroll
      for (int m = 0; m < 2; m++)
        af[m] = *(const short8*)((const char*)Ab + (wr * 32 + m * 16 + fr) * 128 + kx);
#pragma unroll
      for (int n = 0; n < 4; n++)
        bf2[n] = *(const short8*)((const char*)Bb + (wc * 64 + n * 16 + fr) * 128 + kx);
#pragma unroll
      for (int m = 0; m < 2; m++)
#pragma unroll
        for (int n = 0; n < 4; n++)
          acc[m][n] = __builtin_amdgcn_mfma_f32_16x16x32_bf16(af[m], bf2[n], acc[m][n], 0, 0, 0);
    }
  }
#undef STAGE
}

#define LANE_SETUP                                             \
  const int tid = threadIdx.x;                                 \
  const int w = tid >> 6, l = tid & 63;                        \
  const int wr = w >> 1, wc = w & 1;                           \
  const int fr = l & 15, fq = l >> 4;                          \
  const int srow = w * 8 + (l >> 3);                           \
  const int scol = 8 * ((l & 7) ^ (l >> 3));                   \
  const int lbase = w * 512;

#define ACC_INIT(a)                                            \
  _Pragma("unroll") for (int m = 0; m < 2; m++)                \
  _Pragma("unroll") for (int n = 0; n < 4; n++)                \
      a[m][n] = f32x4{0.f, 0.f, 0.f, 0.f};

// Partial GEMM: part[bz*M*N + idx] = A[.,kslice] @ B[.,kslice]^T  (64x128)
__global__ __launch_bounds__(256, 2)
void gpart_k(const unsigned short* __restrict__ A,
             const unsigned short* __restrict__ Bm,
             int N, int Kd, int kslice,
             float* __restrict__ part) {
  __shared__ unsigned short As[3][4096];
  __shared__ unsigned short Bs[3][8192];
  LANE_SETUP
  int bxi = blockIdx.x, byi = blockIdx.y;
  xcd_swz(gridDim.x, bxi, byi);
  const int bm = byi * 64, bn = bxi * 128;
  const int kbase = blockIdx.z * kslice;
  f32x4 acc[2][4];
  ACC_INIT(acc)

  mm_pipe128(A  + (size_t)(bm + srow) * Kd + kbase + scol,
             Bm + (size_t)(bn + srow) * Kd + kbase + scol,
             Kd, kslice >> 6, &As[0][0], &Bs[0][0], lbase, fr, fq, wr, wc, acc);

  float* dst = part + (size_t)blockIdx.z * BB * N;
#pragma unroll
  for (int m = 0; m < 2; m++)
#pragma unroll
    for (int n = 0; n < 4; n++)
#pragma unroll
      for (int j = 0; j < 4; j++) {
        const int row = bm + wr * 32 + m * 16 + fq * 4 + j;
        const int col = bn + wc * 64 + n * 16 + fr;
        dst[(size_t)row * N + col] = acc[m][n][j];
      }
}

// fused: acc_z = u@V (K=CC), acc_gx = r@W^T (K=DD), then prox-x epilogue.
__global__ __launch_bounds__(256, 2)
void zgx_k(const unsigned short* __restrict__ ub,   // (BB,CC)
           const unsigned short* __restrict__ Vt,   // (KK,CC)
           const unsigned short* __restrict__ r,    // (BB,DD)
           const unsigned short* __restrict__ Wb,   // (KK,DD)
           float* __restrict__ x,                   // io
           unsigned short* __restrict__ xb,
           unsigned short* __restrict__ g) {
  __shared__ unsigned short As[3][4096];
  __shared__ unsigned short Bs[3][8192];
  LANE_SETUP
  int bxi = blockIdx.x, byi = blockIdx.y;
  xcd_swz(gridDim.x, bxi, byi);
  const int bm = byi * 64, bn = bxi * 128;
  f32x4 accz[2][4], accg[2][4];
  ACC_INIT(accz)
  ACC_INIT(accg)

  mm_pipe128(ub + (size_t)(bm + srow) * CC + scol,
             Vt + (size_t)(bn + srow) * CC + scol,
             CC, CC / 64, &As[0][0], &Bs[0][0], lbase, fr, fq, wr, wc, accz);
  mm_pipe128(r  + (size_t)(bm + srow) * DD + scol,
             Wb + (size_t)(bn + srow) * DD + scol,
             DD, DD / 64, &As[0][0], &Bs[0][0], lbase, fr, fq, wr, wc, accg);

#pragma unroll
  for (int m = 0; m < 2; m++)
#pragma unroll
    for (int n = 0; n < 4; n++)
#pragma unroll
      for (int j = 0; j < 4; j++) {
        const int row = bm + wr * 32 + m * 16 + fq * 4 + j;
        const int col = bn + wc * 64 + n * 16 + fr;
        const size_t idx = (size_t)row * KK + col;
        const float e = __expf(-accz[m][n][j]);
        const float thr = (LR * GAMMA * 0.5f) * (1.0f + e);
        const float xv = x[idx] - (2.0f * LR) * accg[m][n][j];
        const float xn = fmaxf(xv - thr, 0.f) + fminf(xv + thr, 0.f);
        x[idx] = xn;
        xb[idx] = f2bf(xn);
        g[idx] = f2bf((-0.5f * GAMMA) * e * fabsf(xn));
      }
}

// r = bf16(part0 + part1 - inputs)      over BB*DD
__global__ __launch_bounds__(256) void ep_r_k(const float* __restrict__ part,
                                              const float* __restrict__ inputs,
                                              unsigned short* __restrict__ r) {
  const int i = blockIdx.x * 256 + threadIdx.x;
  const f32x4 s = ((const f32x4*)part)[i] + ((const f32x4*)(part + (size_t)BB * DD))[i]
                - ((const f32x4*)inputs)[i];
  store4bf(r + (size_t)i * 4, s);
}

// out = part0 + part1  (fp32, final step)
__global__ __launch_bounds__(256) void ep_out_k(const float* __restrict__ part,
                                                float* __restrict__ out) {
  const int i = blockIdx.x * 256 + threadIdx.x;
  ((f32x4*)out)[i] = ((const f32x4*)part)[i] + ((const f32x4*)(part + (size_t)BB * DD))[i];
}

// u-update: gu = sum(part[0..7]) + 0.02*GAMMA*u; prox; writes u, ub
__global__ __launch_bounds__(256) void ep_u_k(const float* __restrict__ part,
                                              float* __restrict__ u,
                                              unsigned short* __restrict__ ub) {
  const int i = blockIdx.x * 256 + threadIdx.x;
  f32x4 v = f32x4{0.f, 0.f, 0.f, 0.f};
#pragma unroll
  for (int k = 0; k < 8; k++) v += ((const f32x4*)(part + (size_t)k * BB * CC))[i];
  const f32x4 uo = ((const f32x4*)u)[i];
  f32x4 un;
#pragma unroll
  for (int j = 0; j < 4; j++) {
    const float gu = v[j] + (0.02f * GAMMA) * uo[j];
    const float uu = uo[j] - LR * gu;
    un[j] = fmaxf(uu - (LR * GAMMA), 0.f) + fminf(uu + (LR * GAMMA), 0.f);
  }
  ((f32x4*)u)[i] = un;
  store4bf(ub + (size_t)i * 4, un);
}

// ---- one-time conversion / init kernels ----

__global__ __launch_bounds__(256)
void convtrans_k(const float* __restrict__ src, unsigned short* __restrict__ b,
                 unsigned short* __restrict__ t, int R, int C) {
  __shared__ float tile[64][65];
  const int tid = threadIdx.x;
  const int tr = blockIdx.y * 64;
  const int tc = blockIdx.x * 64;
  const int lr = tid >> 4;
  const int lc = (tid & 15) * 4;
#pragma unroll
  for (int i = 0; i < 4; i++) {
    const float4 v = *(const float4*)(src + (size_t)(tr + lr + 16 * i) * C + tc + lc);
    tile[lr + 16 * i][lc + 0] = v.x;
    tile[lr + 16 * i][lc + 1] = v.y;
    tile[lr + 16 * i][lc + 2] = v.z;
    tile[lr + 16 * i][lc + 3] = v.w;
    store4bf(b + (size_t)(tr + lr + 16 * i) * C + tc + lc, f32x4{v.x, v.y, v.z, v.w});
  }
  __syncthreads();
#pragma unroll
  for (int j = 0; j < 16; j++) {
    const int idx = tid + j * 256;
    const int c = idx >> 6;
    const int r = idx & 63;
    t[(size_t)(tc + c) * R + tr + r] = f2bf(tile[r][c]);
  }
}

__global__ void zero_k(unsigned int* p, int n) {
  const int i = blockIdx.x * blockDim.x + threadIdx.x;
  if (i < n) p[i] = 0u;
}

__global__ void initu_k(const float* __restrict__ u0, float* __restrict__ u,
                        unsigned short* __restrict__ ub, int n) {
  const int i = blockIdx.x * blockDim.x + threadIdx.x;
  if (i < n) {
    const float v = u0[i];
    u[i] = v;
    ub[i] = f2bf(v);
  }
}

__global__ __launch_bounds__(256) void r0_k(const float* __restrict__ inputs,
                                            unsigned short* __restrict__ r) {
  const int i = blockIdx.x * 256 + threadIdx.x;
  const f32x4 v = ((const f32x4*)inputs)[i];
  store4bf(r + (size_t)i * 4, f32x4{0.f, 0.f, 0.f, 0.f} - v);
}

extern "C" void kernel_launch(void* const* d_in, const int* in_sizes, int n_in,
                              void* d_out, int out_size, void* d_ws, size_t ws_size,
                              hipStream_t stream) {
  const float* inputs = (const float*)d_in[0];   // (BB, DD)
  const float* W      = (const float*)d_in[1];   // (KK, DD)
  const float* V      = (const float*)d_in[2];   // (CC, KK)
  const float* u0     = (const float*)d_in[3];   // (BB, CC)
  float* out = (float*)d_out;                    // (BB, DD)

  char* ws = (char*)d_ws;
  size_t off = 0;
  auto alloc = [&](size_t bytes) -> void* {
    void* p = ws + off;
    off += (bytes + 255) & ~(size_t)255;
    return p;
  };
  unsigned short* Wb = (unsigned short*)alloc((size_t)KK * DD * 2);  // W  (KK,DD)
  unsigned short* Wt = (unsigned short*)alloc((size_t)DD * KK * 2);  // W^T (DD,KK)
  unsigned short* Vb = (unsigned short*)alloc((size_t)CC * KK * 2);  // V  (CC,KK)
  unsigned short* Vt = (unsigned short*)alloc((size_t)KK * CC * 2);  // V^T (KK,CC)
  unsigned short* xb = (unsigned short*)alloc((size_t)BB * KK * 2);
  unsigned short* g  = (unsigned short*)alloc((size_t)BB * KK * 2);
  unsigned short* r  = (unsigned short*)alloc((size_t)BB * DD * 2);
  unsigned short* ub = (unsigned short*)alloc((size_t)BB * CC * 2);
  float* x = (float*)alloc((size_t)BB * KK * 4);
  float* u = (float*)alloc((size_t)BB * CC * 4);
  float* part = (float*)alloc((size_t)8 * BB * CC * 4);  // 8MB: max(2*B*D, 8*B*C)*4

  convtrans_k<<<dim3(DD / 64, KK / 64), 256, 0, stream>>>(W, Wb, Wt, KK, DD);
  convtrans_k<<<dim3(KK / 64, CC / 64), 256, 0, stream>>>(V, Vb, Vt, CC, KK);
  zero_k<<<(BB * KK / 2 + 255) / 256, 256, 0, stream>>>((unsigned int*)xb, BB * KK / 2);
  zero_k<<<(BB * KK + 255) / 256, 256, 0, stream>>>((unsigned int*)x, BB * KK);
  initu_k<<<(BB * CC + 255) / 256, 256, 0, stream>>>(u0, u, ub, BB * CC);
  r0_k<<<BB * DD / 4 / 256, 256, 0, stream>>>(inputs, r);

  for (int t = 0; t < 10; t++) {
    if (t > 0) {
      // out-partials: x@W, 64x128 tiles, split-K=2 -> 16x8x2 = 256 wgs
      gpart_k<<<dim3(DD / 128, BB / 64, 2), 256, 0, stream>>>(xb, Wt, DD, KK, KK / 2, part);
      if (t < 9) {
        ep_r_k<<<BB * DD / 4 / 256, 256, 0, stream>>>(part, inputs, r);
      } else {
        ep_out_k<<<BB * DD / 4 / 256, 256, 0, stream>>>(part, out);
        break;
      }
    }
    // z = u@V then gradx = 2*r@W^T, fused prox-x: 32x8 = 256 wgs
    zgx_k<<<dim3(KK / 128, BB / 64), 256, 0, stream>>>(ub, Vt, r, Wb, x, xb, g);
    // gu partials: g@V^T split-K=8: 4x8x8 = 256 wgs
    gpart_k<<<dim3(CC / 128, BB / 64, 8), 256, 0, stream>>>(g, Vb, CC, KK, KK / 8, part);
    ep_u_k<<<BB * CC / 4 / 256, 256, 0, stream>>>(part, u, ub);
  }
}

// Round 6
// 598.882 us; speedup vs baseline: 1.2674x; 1.2674x over previous
//
#include <hip/hip_runtime.h>
#include <hip/hip_bf16.h>

#define BB 512      // batch
#define DD 2048     // input dim
#define KK 4096     // code dim
#define CC 512      // cause dim
#define LR 0.001f
#define GAMMA 0.1f

typedef __attribute__((ext_vector_type(8))) short short8;
typedef __attribute__((ext_vector_type(4))) float f32x4;

__device__ __forceinline__ unsigned short f2bf(float f) {
  union { float f; unsigned u; } x; x.f = f;
  unsigned r = x.u + 0x7FFF + ((x.u >> 16) & 1);   // RNE
  return (unsigned short)(r >> 16);
}

__device__ __forceinline__ void g2l16(const void* g, void* l) {
  __builtin_amdgcn_global_load_lds(
      (const __attribute__((address_space(1))) void*)g,
      (__attribute__((address_space(3))) void*)l, 16, 0, 0);
}

__device__ __forceinline__ void store4bf(unsigned short* p, f32x4 v) {
  const unsigned lo = (unsigned)f2bf(v[0]) | ((unsigned)f2bf(v[1]) << 16);
  const unsigned hi = (unsigned)f2bf(v[2]) | ((unsigned)f2bf(v[3]) << 16);
  *(uint2*)p = uint2{lo, hi};
}

// ---------------------------------------------------------------------------
// 64x64-tile K-loop, BK=64, 4 waves (2x2), wave tile 32x32 (8 MFMA/wave/iter).
// NBUF LDS buffer sets, (NBUF-1) tiles staged ahead, stage issued RIGHT AFTER
// the barrier (before compute) so loads overlap the MFMA block. Counted vmcnt
// (4 loads per wave per tile). XOR-swizzled LDS via pre-swizzled global src
// (rule #21). Single barrier/iter: a wave's iter-(t-1) ds_reads retire before
// its MFMAs (compiler lgkm waits) which precede the barrier, so restaging
// buf (t+NBUF-1)%NBUF after barrier(t) is race-free.
// ---------------------------------------------------------------------------
template<int NBUF>
__device__ __forceinline__ void mm_tile(
    const unsigned short* __restrict__ ag,   // lane-adjusted A base
    const unsigned short* __restrict__ bg,   // lane-adjusted B base
    int Kd, int nt,
    unsigned short* As, unsigned short* Bs,  // [NBUF][4096] each
    int lbase, int fr, int fq, int wr, int wc,
    f32x4 acc[2][2]) {
  auto STG = [&](int ti, int buf) {
    const int k0 = ti << 6;
    unsigned short* Ab = As + buf * 4096;
    unsigned short* Bb = Bs + buf * 4096;
    g2l16(ag + k0, Ab + lbase);
    g2l16(ag + (size_t)32 * Kd + k0, Ab + 2048 + lbase);
    g2l16(bg + k0, Bb + lbase);
    g2l16(bg + (size_t)32 * Kd + k0, Bb + 2048 + lbase);
  };
#pragma unroll
  for (int p = 0; p < NBUF - 1; p++)
    if (p < nt) STG(p, p);

  int cb = 0, sb = NBUF - 1;
  for (int t = 0; t < nt; t++) {
    if constexpr (NBUF == 4) {
      if (t + 3 < nt)      asm volatile("s_waitcnt vmcnt(8)" ::: "memory");
      else if (t + 2 < nt) asm volatile("s_waitcnt vmcnt(4)" ::: "memory");
      else                 asm volatile("s_waitcnt vmcnt(0)" ::: "memory");
    } else {  // NBUF == 3
      if (t + 2 < nt)      asm volatile("s_waitcnt vmcnt(4)" ::: "memory");
      else                 asm volatile("s_waitcnt vmcnt(0)" ::: "memory");
    }
    __builtin_amdgcn_s_barrier();
    if (t + NBUF - 1 < nt) STG(t + NBUF - 1, sb);

    const unsigned short* Ab = As + cb * 4096;
    const unsigned short* Bb = Bs + cb * 4096;
#pragma unroll
    for (int kk = 0; kk < 2; kk++) {
      const int kx = (kk * 64 + fq * 16) ^ ((fr & 7) << 4);
      short8 af[2], bf2[2];
#pragma unroll
      for (int m = 0; m < 2; m++)
        af[m] = *(const short8*)((const char*)Ab + (wr * 32 + m * 16 + fr) * 128 + kx);
#pragma unroll
      for (int n = 0; n < 2; n++)
        bf2[n] = *(const short8*)((const char*)Bb + (wc * 32 + n * 16 + fr) * 128 + kx);
#pragma unroll
      for (int m = 0; m < 2; m++)
#pragma unroll
        for (int n = 0; n < 2; n++)
          acc[m][n] = __builtin_amdgcn_mfma_f32_16x16x32_bf16(af[m], bf2[n], acc[m][n], 0, 0, 0);
    }
    cb = (cb + 1 == NBUF) ? 0 : cb + 1;
    sb = (sb + 1 == NBUF) ? 0 : sb + 1;
  }
  // LDS safe for next use (vmcnt already 0 after last iter)
  asm volatile("s_waitcnt lgkmcnt(0)" ::: "memory");
  __builtin_amdgcn_s_barrier();
}

#define LANE_SETUP                                             \
  const int tid = threadIdx.x;                                 \
  const int w = tid >> 6, l = tid & 63;                        \
  const int wr = w >> 1, wc = w & 1;                           \
  const int fr = l & 15, fq = l >> 4;                          \
  const int srow = w * 8 + (l >> 3);                           \
  const int scol = 8 * ((l & 7) ^ (l >> 3));                   \
  const int lbase = w * 512;

#define ACC_INIT(a)                                            \
  _Pragma("unroll") for (int m = 0; m < 2; m++)                \
  _Pragma("unroll") for (int n = 0; n < 2; n++)                \
      a[m][n] = f32x4{0.f, 0.f, 0.f, 0.f};

// K1: jobs [jobbase, jobbase+grid): j<512 -> out-split2 partials (32 iters),
//     j>=512 -> z tiles (8 iters). 48KB LDS -> 3 blocks/CU.
__global__ __launch_bounds__(256, 2)
void ozp_k(const unsigned short* __restrict__ xb,   // (BB,KK)
           const unsigned short* __restrict__ Wt,   // (DD,KK)
           const unsigned short* __restrict__ ub,   // (BB,CC)
           const unsigned short* __restrict__ Vt,   // (KK,CC)
           float* __restrict__ part,                // 2 x (BB,DD)
           float* __restrict__ z,                   // (BB,KK)
           int jobbase) {
  __shared__ unsigned short As[3][4096];
  __shared__ unsigned short Bs[3][4096];
  LANE_SETUP
  const int job = blockIdx.x + jobbase;
  f32x4 acc[2][2];
  ACC_INIT(acc)
  if (job < 512) {
    const int T = job >> 1, ks = job & 1;
    const int bm = (T >> 5) * 64, bn = (T & 31) * 64;
    mm_tile<3>(xb + (size_t)(bm + srow) * KK + ks * 2048 + scol,
               Wt + (size_t)(bn + srow) * KK + ks * 2048 + scol,
               KK, 32, &As[0][0], &Bs[0][0], lbase, fr, fq, wr, wc, acc);
    float* dst = part + (size_t)ks * BB * DD;
#pragma unroll
    for (int m = 0; m < 2; m++)
#pragma unroll
      for (int n = 0; n < 2; n++)
#pragma unroll
        for (int j = 0; j < 4; j++)
          dst[(size_t)(bm + wr * 32 + m * 16 + fq * 4 + j) * DD
              + bn + wc * 32 + n * 16 + fr] = acc[m][n][j];
  } else {
    const int T = job - 512;
    const int bm = (T >> 6) * 64, bn = (T & 63) * 64;
    mm_tile<3>(ub + (size_t)(bm + srow) * CC + scol,
               Vt + (size_t)(bn + srow) * CC + scol,
               CC, 8, &As[0][0], &Bs[0][0], lbase, fr, fq, wr, wc, acc);
#pragma unroll
    for (int m = 0; m < 2; m++)
#pragma unroll
      for (int n = 0; n < 2; n++)
#pragma unroll
        for (int j = 0; j < 4; j++)
          z[(size_t)(bm + wr * 32 + m * 16 + fq * 4 + j) * KK
            + bn + wc * 32 + n * 16 + fr] = acc[m][n][j];
  }
}

// K3: gradx = 2*r@W^T with fused prox-x epilogue. 64KB LDS -> 2 blocks/CU.
__global__ __launch_bounds__(256, 2)
void gx_k(const unsigned short* __restrict__ r,    // (BB,DD)
          const unsigned short* __restrict__ Wb,   // (KK,DD)
          const float* __restrict__ z,             // (BB,KK)
          float* __restrict__ x,                   // io
          unsigned short* __restrict__ xb,
          unsigned short* __restrict__ g) {
  __shared__ unsigned short As[4][4096];
  __shared__ unsigned short Bs[4][4096];
  LANE_SETUP
  const int bm = (blockIdx.x >> 6) * 64, bn = (blockIdx.x & 63) * 64;
  f32x4 acc[2][2];
  ACC_INIT(acc)
  mm_tile<4>(r  + (size_t)(bm + srow) * DD + scol,
             Wb + (size_t)(bn + srow) * DD + scol,
             DD, 32, &As[0][0], &Bs[0][0], lbase, fr, fq, wr, wc, acc);
#pragma unroll
  for (int m = 0; m < 2; m++)
#pragma unroll
    for (int n = 0; n < 2; n++)
#pragma unroll
      for (int j = 0; j < 4; j++) {
        const int row = bm + wr * 32 + m * 16 + fq * 4 + j;
        const int col = bn + wc * 32 + n * 16 + fr;
        const size_t idx = (size_t)row * KK + col;
        const float e = __expf(-z[idx]);
        const float thr = (LR * GAMMA * 0.5f) * (1.0f + e);
        const float xv = x[idx] - (2.0f * LR) * acc[m][n][j];
        const float xn = fmaxf(xv - thr, 0.f) + fminf(xv + thr, 0.f);
        x[idx] = xn;
        xb[idx] = f2bf(xn);
        g[idx] = f2bf((-0.5f * GAMMA) * e * fabsf(xn));
      }
}

// K4: gu partials, split-K=8: part[ks*BB*CC + idx] = g@V^T over K-slice
__global__ __launch_bounds__(256, 2)
void gup_k(const unsigned short* __restrict__ g,    // (BB,KK)
           const unsigned short* __restrict__ Vb,   // (CC,KK)
           float* __restrict__ part) {
  __shared__ unsigned short As[3][4096];
  __shared__ unsigned short Bs[3][4096];
  LANE_SETUP
  const int j = blockIdx.x;
  const int T = j >> 3, ks = j & 7;
  const int bm = (T >> 3) * 64, bn = (T & 7) * 64;
  f32x4 acc[2][2];
  ACC_INIT(acc)
  mm_tile<3>(g  + (size_t)(bm + srow) * KK + ks * 512 + scol,
             Vb + (size_t)(bn + srow) * KK + ks * 512 + scol,
             KK, 8, &As[0][0], &Bs[0][0], lbase, fr, fq, wr, wc, acc);
  float* dst = part + (size_t)ks * BB * CC;
#pragma unroll
  for (int m = 0; m < 2; m++)
#pragma unroll
    for (int n = 0; n < 2; n++)
#pragma unroll
      for (int j2 = 0; j2 < 4; j2++)
        dst[(size_t)(bm + wr * 32 + m * 16 + fq * 4 + j2) * CC
            + bn + wc * 32 + n * 16 + fr] = acc[m][n][j2];
}

// ---- elementwise epilogues ----

__global__ __launch_bounds__(256) void ep_r_k(const float* __restrict__ part,
                                              const float* __restrict__ inputs,
                                              unsigned short* __restrict__ r) {
  const int i = blockIdx.x * 256 + threadIdx.x;
  const f32x4 s = ((const f32x4*)part)[i] + ((const f32x4*)(part + (size_t)BB * DD))[i]
                - ((const f32x4*)inputs)[i];
  store4bf(r + (size_t)i * 4, s);
}

__global__ __launch_bounds__(256) void ep_out_k(const float* __restrict__ part,
                                                float* __restrict__ out) {
  const int i = blockIdx.x * 256 + threadIdx.x;
  ((f32x4*)out)[i] = ((const f32x4*)part)[i] + ((const f32x4*)(part + (size_t)BB * DD))[i];
}

__global__ __launch_bounds__(256) void ep_u_k(const float* __restrict__ part,
                                              float* __restrict__ u,
                                              unsigned short* __restrict__ ub) {
  const int i = blockIdx.x * 256 + threadIdx.x;
  f32x4 v = f32x4{0.f, 0.f, 0.f, 0.f};
#pragma unroll
  for (int k = 0; k < 8; k++) v += ((const f32x4*)(part + (size_t)k * BB * CC))[i];
  const f32x4 uo = ((const f32x4*)u)[i];
  f32x4 un;
#pragma unroll
  for (int j = 0; j < 4; j++) {
    const float gu = v[j] + (0.02f * GAMMA) * uo[j];
    const float uu = uo[j] - LR * gu;
    un[j] = fmaxf(uu - (LR * GAMMA), 0.f) + fminf(uu + (LR * GAMMA), 0.f);
  }
  ((f32x4*)u)[i] = un;
  store4bf(ub + (size_t)i * 4, un);
}

// ---- one-time conversion / init kernels ----

__global__ __launch_bounds__(256)
void convtrans_k(const float* __restrict__ src, unsigned short* __restrict__ b,
                 unsigned short* __restrict__ t, int R, int C) {
  __shared__ float tile[64][65];
  const int tid = threadIdx.x;
  const int tr = blockIdx.y * 64;
  const int tc = blockIdx.x * 64;
  const int lr = tid >> 4;
  const int lc = (tid & 15) * 4;
#pragma unroll
  for (int i = 0; i < 4; i++) {
    const float4 v = *(const float4*)(src + (size_t)(tr + lr + 16 * i) * C + tc + lc);
    tile[lr + 16 * i][lc + 0] = v.x;
    tile[lr + 16 * i][lc + 1] = v.y;
    tile[lr + 16 * i][lc + 2] = v.z;
    tile[lr + 16 * i][lc + 3] = v.w;
    store4bf(b + (size_t)(tr + lr + 16 * i) * C + tc + lc, f32x4{v.x, v.y, v.z, v.w});
  }
  __syncthreads();
#pragma unroll
  for (int j = 0; j < 16; j++) {
    const int idx = tid + j * 256;
    const int c = idx >> 6;
    const int r = idx & 63;
    t[(size_t)(tc + c) * R + tr + r] = f2bf(tile[r][c]);
  }
}

__global__ void zero_k(unsigned int* p, int n) {
  const int i = blockIdx.x * blockDim.x + threadIdx.x;
  if (i < n) p[i] = 0u;
}

__global__ void initu_k(const float* __restrict__ u0, float* __restrict__ u,
                        unsigned short* __restrict__ ub, int n) {
  const int i = blockIdx.x * blockDim.x + threadIdx.x;
  if (i < n) {
    const float v = u0[i];
    u[i] = v;
    ub[i] = f2bf(v);
  }
}

__global__ __launch_bounds__(256) void r0_k(const float* __restrict__ inputs,
                                            unsigned short* __restrict__ r) {
  const int i = blockIdx.x * 256 + threadIdx.x;
  const f32x4 v = ((const f32x4*)inputs)[i];
  store4bf(r + (size_t)i * 4, f32x4{0.f, 0.f, 0.f, 0.f} - v);
}

extern "C" void kernel_launch(void* const* d_in, const int* in_sizes, int n_in,
                              void* d_out, int out_size, void* d_ws, size_t ws_size,
                              hipStream_t stream) {
  const float* inputs = (const float*)d_in[0];   // (BB, DD)
  const float* W      = (const float*)d_in[1];   // (KK, DD)
  const float* V      = (const float*)d_in[2];   // (CC, KK)
  const float* u0     = (const float*)d_in[3];   // (BB, CC)
  float* out = (float*)d_out;                    // (BB, DD)

  char* ws = (char*)d_ws;
  size_t off = 0;
  auto alloc = [&](size_t bytes) -> void* {
    void* p = ws + off;
    off += (bytes + 255) & ~(size_t)255;
    return p;
  };
  unsigned short* Wb = (unsigned short*)alloc((size_t)KK * DD * 2);  // W  (KK,DD)
  unsigned short* Wt = (unsigned short*)alloc((size_t)DD * KK * 2);  // W^T (DD,KK)
  unsigned short* Vb = (unsigned short*)alloc((size_t)CC * KK * 2);  // V  (CC,KK)
  unsigned short* Vt = (unsigned short*)alloc((size_t)KK * CC * 2);  // V^T (KK,CC)
  unsigned short* xb = (unsigned short*)alloc((size_t)BB * KK * 2);
  unsigned short* g  = (unsigned short*)alloc((size_t)BB * KK * 2);
  unsigned short* r  = (unsigned short*)alloc((size_t)BB * DD * 2);
  unsigned short* ub = (unsigned short*)alloc((size_t)BB * CC * 2);
  float* x = (float*)alloc((size_t)BB * KK * 4);
  float* z = (float*)alloc((size_t)BB * KK * 4);
  float* u = (float*)alloc((size_t)BB * CC * 4);
  float* part = (float*)alloc((size_t)8 * BB * CC * 4);  // 8MB: out(2xBBxDD) / gu(8xBBxCC)

  convtrans_k<<<dim3(DD / 64, KK / 64), 256, 0, stream>>>(W, Wb, Wt, KK, DD);
  convtrans_k<<<dim3(KK / 64, CC / 64), 256, 0, stream>>>(V, Vb, Vt, CC, KK);
  zero_k<<<(BB * KK / 2 + 255) / 256, 256, 0, stream>>>((unsigned int*)xb, BB * KK / 2);
  zero_k<<<(BB * KK + 255) / 256, 256, 0, stream>>>((unsigned int*)x, BB * KK);
  initu_k<<<(BB * CC + 255) / 256, 256, 0, stream>>>(u0, u, ub, BB * CC);
  r0_k<<<BB * DD / 4 / 256, 256, 0, stream>>>(inputs, r);

  for (int t = 0; t < 10; t++) {
    if (t == 0) {
      // z only (x=0, r already = -inputs)
      ozp_k<<<512, 256, 0, stream>>>(xb, Wt, ub, Vt, part, z, 512);
    } else if (t < 9) {
      // out-split2 partials + z, concurrent in one launch
      ozp_k<<<1024, 256, 0, stream>>>(xb, Wt, ub, Vt, part, z, 0);
      ep_r_k<<<BB * DD / 4 / 256, 256, 0, stream>>>(part, inputs, r);
    } else {
      // final: out partials only, then fp32 sum to d_out
      ozp_k<<<512, 256, 0, stream>>>(xb, Wt, ub, Vt, part, z, 0);
      ep_out_k<<<BB * DD / 4 / 256, 256, 0, stream>>>(part, out);
      break;
    }
    gx_k<<<512, 256, 0, stream>>>(r, Wb, z, x, xb, g);
    gup_k<<<512, 256, 0, stream>>>(g, Vb, part);
    ep_u_k<<<BB * CC / 4 / 256, 256, 0, stream>>>(part, u, ub);
  }
}

// Round 8
// 546.145 us; speedup vs baseline: 1.3898x; 1.0966x over previous
//
#include <hip/hip_runtime.h>
#include <hip/hip_bf16.h>

#define BB 512      // batch
#define DD 2048     // input dim
#define KK 4096     // code dim
#define CC 512      // cause dim
#define LR 0.001f
#define GAMMA 0.1f

typedef __attribute__((ext_vector_type(8))) short short8;
typedef __attribute__((ext_vector_type(4))) float f32x4;

__device__ __forceinline__ unsigned short f2bf(float f) {
  union { float f; unsigned u; } x; x.f = f;
  unsigned r = x.u + 0x7FFF + ((x.u >> 16) & 1);   // RNE
  return (unsigned short)(r >> 16);
}

__device__ __forceinline__ void g2l16(const void* g, void* l) {
  __builtin_amdgcn_global_load_lds(
      (const __attribute__((address_space(1))) void*)g,
      (__attribute__((address_space(3))) void*)l, 16, 0, 0);
}

__device__ __forceinline__ void store4bf(unsigned short* p, f32x4 v) {
  const unsigned lo = (unsigned)f2bf(v[0]) | ((unsigned)f2bf(v[1]) << 16);
  const unsigned hi = (unsigned)f2bf(v[2]) | ((unsigned)f2bf(v[3]) << 16);
  *(uint2*)p = uint2{lo, hi};
}

// ---------------------------------------------------------------------------
// 64x64-tile K-loop, BK=64, 4 waves (2x2), wave tile 32x32 (8 MFMA/wave/iter).
// 3 LDS buffer sets (48 KB -> 3 blocks/CU), 2 tiles staged ahead, stage
// issued right after the barrier so loads overlap the MFMA block. Counted
// vmcnt (4 loads/wave/tile). XOR-swizzled LDS via pre-swizzled global source
// (rule #21). Single barrier/iter (wait-own-vmcnt THEN barrier => all waves'
// staging for tile t visible). Restage into buf (t+2)%3 is race-free: that
// buffer was consumed at iter t-1 and barrier(t) proves all waves passed it.
// ---------------------------------------------------------------------------
__device__ __forceinline__ void mm_tile(
    const unsigned short* __restrict__ ag,   // lane-adjusted A base
    const unsigned short* __restrict__ bg,   // lane-adjusted B base
    int Kd, int nt,
    unsigned short* As, unsigned short* Bs,  // [3][4096] each
    int lbase, int fr, int fq, int wr, int wc,
    f32x4 acc[2][2]) {
  auto STG = [&](int ti, int buf) {
    const int k0 = ti << 6;
    unsigned short* Ab = As + buf * 4096;
    unsigned short* Bb = Bs + buf * 4096;
    g2l16(ag + k0, Ab + lbase);
    g2l16(ag + (size_t)32 * Kd + k0, Ab + 2048 + lbase);
    g2l16(bg + k0, Bb + lbase);
    g2l16(bg + (size_t)32 * Kd + k0, Bb + 2048 + lbase);
  };
#pragma unroll
  for (int p = 0; p < 2; p++)
    if (p < nt) STG(p, p);

  int cb = 0, sb = 2;
  for (int t = 0; t < nt; t++) {
    if (t + 1 < nt) asm volatile("s_waitcnt vmcnt(4)" ::: "memory");
    else            asm volatile("s_waitcnt vmcnt(0)" ::: "memory");
    __builtin_amdgcn_s_barrier();
    if (t + 2 < nt) STG(t + 2, sb);

    const unsigned short* Ab = As + cb * 4096;
    const unsigned short* Bb = Bs + cb * 4096;
#pragma unroll
    for (int kk = 0; kk < 2; kk++) {
      const int kx = (kk * 64 + fq * 16) ^ ((fr & 7) << 4);
      short8 af[2], bf2[2];
#pragma unroll
      for (int m = 0; m < 2; m++)
        af[m] = *(const short8*)((const char*)Ab + (wr * 32 + m * 16 + fr) * 128 + kx);
#pragma unroll
      for (int n = 0; n < 2; n++)
        bf2[n] = *(const short8*)((const char*)Bb + (wc * 32 + n * 16 + fr) * 128 + kx);
#pragma unroll
      for (int m = 0; m < 2; m++)
#pragma unroll
        for (int n = 0; n < 2; n++)
          acc[m][n] = __builtin_amdgcn_mfma_f32_16x16x32_bf16(af[m], bf2[n], acc[m][n], 0, 0, 0);
    }
    cb = (cb + 1 == 3) ? 0 : cb + 1;
    sb = (sb + 1 == 3) ? 0 : sb + 1;
  }
}

#define LANE_SETUP                                             \
  const int tid = threadIdx.x;                                 \
  const int w = tid >> 6, l = tid & 63;                        \
  const int wr = w >> 1, wc = w & 1;                           \
  const int fr = l & 15, fq = l >> 4;                          \
  const int srow = w * 8 + (l >> 3);                           \
  const int scol = 8 * ((l & 7) ^ (l >> 3));                   \
  const int lbase = w * 512;

#define ACC_INIT(a)                                            \
  _Pragma("unroll") for (int m = 0; m < 2; m++)                \
  _Pragma("unroll") for (int n = 0; n < 2; n++)                \
      a[m][n] = f32x4{0.f, 0.f, 0.f, 0.f};

#define ACC_STORE(dst, N)                                      \
  _Pragma("unroll") for (int m = 0; m < 2; m++)                \
  _Pragma("unroll") for (int n = 0; n < 2; n++)                \
  _Pragma("unroll") for (int j2 = 0; j2 < 4; j2++)             \
      (dst)[(size_t)(bm + wr * 32 + m * 16 + fq * 4 + j2) * (N)\
            + bn + wc * 32 + n * 16 + fr] = acc[m][n][j2];

// Launch A: j<1024 -> gx partials (split-K=2, 16 iters): gxp[ks] = r@Wb^T slice
//           j>=1024 -> z tiles (8 iters): z = ub@Vt^T
__global__ __launch_bounds__(256, 3)
void zgxp_k(const unsigned short* __restrict__ r,    // (BB,DD)
            const unsigned short* __restrict__ Wb,   // (KK,DD)
            const unsigned short* __restrict__ ub,   // (BB,CC)
            const unsigned short* __restrict__ Vt,   // (KK,CC)
            float* __restrict__ gxp,                 // 2 x (BB,KK)
            float* __restrict__ z) {                 // (BB,KK)
  __shared__ unsigned short As[3][4096];
  __shared__ unsigned short Bs[3][4096];
  LANE_SETUP
  const int j = blockIdx.x;
  f32x4 acc[2][2];
  ACC_INIT(acc)
  if (j < 1024) {
    const int T = j >> 1, ks = j & 1;
    const int bm = (T >> 6) * 64, bn = (T & 63) * 64;
    mm_tile(r  + (size_t)(bm + srow) * DD + ks * 1024 + scol,
            Wb + (size_t)(bn + srow) * DD + ks * 1024 + scol,
            DD, 16, &As[0][0], &Bs[0][0], lbase, fr, fq, wr, wc, acc);
    float* dst = gxp + (size_t)ks * BB * KK;
    ACC_STORE(dst, KK)
  } else {
    const int T = j - 1024;
    const int bm = (T >> 6) * 64, bn = (T & 63) * 64;
    mm_tile(ub + (size_t)(bm + srow) * CC + scol,
            Vt + (size_t)(bn + srow) * CC + scol,
            CC, 8, &As[0][0], &Bs[0][0], lbase, fr, fq, wr, wc, acc);
    ACC_STORE(z, KK)
  }
}

// Launch C: j<1024 -> out partials (split-K=4, 16 iters): outp[ks] = xb@Wt^T
//           j>=1024 -> gu partials (split-K=8, 8 iters): gup[ks] = g@Vb^T
__global__ __launch_bounds__(256, 3)
void cgo_k(const unsigned short* __restrict__ xb,   // (BB,KK)
           const unsigned short* __restrict__ Wt,   // (DD,KK)
           const unsigned short* __restrict__ g,    // (BB,KK)
           const unsigned short* __restrict__ Vb,   // (CC,KK)
           float* __restrict__ outp,                // 4 x (BB,DD)
           float* __restrict__ gup) {               // 8 x (BB,CC)
  __shared__ unsigned short As[3][4096];
  __shared__ unsigned short Bs[3][4096];
  LANE_SETUP
  const int j = blockIdx.x;
  f32x4 acc[2][2];
  ACC_INIT(acc)
  if (j < 1024) {
    const int T = j >> 2, ks = j & 3;
    const int bm = (T >> 5) * 64, bn = (T & 31) * 64;
    mm_tile(xb + (size_t)(bm + srow) * KK + ks * 1024 + scol,
            Wt + (size_t)(bn + srow) * KK + ks * 1024 + scol,
            KK, 16, &As[0][0], &Bs[0][0], lbase, fr, fq, wr, wc, acc);
    float* dst = outp + (size_t)ks * BB * DD;
    ACC_STORE(dst, DD)
  } else {
    const int jj = j - 1024;
    const int T = jj >> 3, ks = jj & 7;
    const int bm = (T >> 3) * 64, bn = (T & 7) * 64;
    mm_tile(g  + (size_t)(bm + srow) * KK + ks * 512 + scol,
            Vb + (size_t)(bn + srow) * KK + ks * 512 + scol,
            KK, 8, &As[0][0], &Bs[0][0], lbase, fr, fq, wr, wc, acc);
    float* dst = gup + (size_t)ks * BB * CC;
    ACC_STORE(dst, CC)
  }
}

// Launch B: prox-x over BB*KK: v = gxp0+gxp1; x=prox(x-2lr*v, lr*g*causes(z));
// writes x, xb, g
__global__ __launch_bounds__(256) void ep_x_k(const float* __restrict__ gxp,
                                              const float* __restrict__ z,
                                              float* __restrict__ x,
                                              unsigned short* __restrict__ xb,
                                              unsigned short* __restrict__ g) {
  const int i = blockIdx.x * 256 + threadIdx.x;
  const f32x4 v = ((const f32x4*)gxp)[i] + ((const f32x4*)(gxp + (size_t)BB * KK))[i];
  const f32x4 zv = ((const f32x4*)z)[i];
  const f32x4 xo = ((const f32x4*)x)[i];
  f32x4 xn, gg;
#pragma unroll
  for (int j = 0; j < 4; j++) {
    const float e = __expf(-zv[j]);
    const float thr = (LR * GAMMA * 0.5f) * (1.0f + e);
    const float xv = xo[j] - (2.0f * LR) * v[j];
    const float t = fmaxf(xv - thr, 0.f) + fminf(xv + thr, 0.f);
    xn[j] = t;
    gg[j] = (-0.5f * GAMMA) * e * fabsf(t);
  }
  ((f32x4*)x)[i] = xn;
  store4bf(xb + (size_t)i * 4, xn);
  store4bf(g + (size_t)i * 4, gg);
}

// Launch D: j<256  -> u-update (sum 8 gup + prox -> u, ub)     [256 blocks]
//           j>=256 -> r = bf16(sum 4 outp - inputs)            [1024 blocks]
__global__ __launch_bounds__(256) void ud_k(const float* __restrict__ gup,
                                            const float* __restrict__ outp,
                                            const float* __restrict__ inputs,
                                            float* __restrict__ u,
                                            unsigned short* __restrict__ ub,
                                            unsigned short* __restrict__ r) {
  const int j = blockIdx.x;
  if (j < 256) {
    const int i = j * 256 + threadIdx.x;
    f32x4 v = f32x4{0.f, 0.f, 0.f, 0.f};
#pragma unroll
    for (int k = 0; k < 8; k++) v += ((const f32x4*)(gup + (size_t)k * BB * CC))[i];
    const f32x4 uo = ((const f32x4*)u)[i];
    f32x4 un;
#pragma unroll
    for (int jj = 0; jj < 4; jj++) {
      const float gv = v[jj] + (0.02f * GAMMA) * uo[jj];
      const float uu = uo[jj] - LR * gv;
      un[jj] = fmaxf(uu - (LR * GAMMA), 0.f) + fminf(uu + (LR * GAMMA), 0.f);
    }
    ((f32x4*)u)[i] = un;
    store4bf(ub + (size_t)i * 4, un);
  } else {
    // r-branch needs BB*DD/4 = 262144 lanes = 1024 blocks (R7 bug: had 512)
    const int i = (j - 256) * 256 + threadIdx.x;
    f32x4 s = f32x4{0.f, 0.f, 0.f, 0.f};
#pragma unroll
    for (int k = 0; k < 4; k++) s += ((const f32x4*)(outp + (size_t)k * BB * DD))[i];
    s -= ((const f32x4*)inputs)[i];
    store4bf(r + (size_t)i * 4, s);
  }
}

// final: out = sum 4 outp (fp32)
__global__ __launch_bounds__(256) void ep_out_k(const float* __restrict__ outp,
                                                float* __restrict__ out) {
  const int i = blockIdx.x * 256 + threadIdx.x;
  f32x4 s = f32x4{0.f, 0.f, 0.f, 0.f};
#pragma unroll
  for (int k = 0; k < 4; k++) s += ((const f32x4*)(outp + (size_t)k * BB * DD))[i];
  ((f32x4*)out)[i] = s;
}

// ---- one-time conversion / init kernels ----

__global__ __launch_bounds__(256)
void convtrans_k(const float* __restrict__ src, unsigned short* __restrict__ b,
                 unsigned short* __restrict__ t, int R, int C) {
  __shared__ float tile[64][65];
  const int tid = threadIdx.x;
  const int tr = blockIdx.y * 64;
  const int tc = blockIdx.x * 64;
  const int lr = tid >> 4;
  const int lc = (tid & 15) * 4;
#pragma unroll
  for (int i = 0; i < 4; i++) {
    const float4 v = *(const float4*)(src + (size_t)(tr + lr + 16 * i) * C + tc + lc);
    tile[lr + 16 * i][lc + 0] = v.x;
    tile[lr + 16 * i][lc + 1] = v.y;
    tile[lr + 16 * i][lc + 2] = v.z;
    tile[lr + 16 * i][lc + 3] = v.w;
    store4bf(b + (size_t)(tr + lr + 16 * i) * C + tc + lc, f32x4{v.x, v.y, v.z, v.w});
  }
  __syncthreads();
#pragma unroll
  for (int j = 0; j < 16; j++) {
    const int idx = tid + j * 256;
    const int c = idx >> 6;
    const int r = idx & 63;
    t[(size_t)(tc + c) * R + tr + r] = f2bf(tile[r][c]);
  }
}

__global__ void zero_k(unsigned int* p, int n) {
  const int i = blockIdx.x * blockDim.x + threadIdx.x;
  if (i < n) p[i] = 0u;
}

__global__ void initu_k(const float* __restrict__ u0, float* __restrict__ u,
                        unsigned short* __restrict__ ub, int n) {
  const int i = blockIdx.x * blockDim.x + threadIdx.x;
  if (i < n) {
    const float v = u0[i];
    u[i] = v;
    ub[i] = f2bf(v);
  }
}

__global__ __launch_bounds__(256) void r0_k(const float* __restrict__ inputs,
                                            unsigned short* __restrict__ r) {
  const int i = blockIdx.x * 256 + threadIdx.x;
  const f32x4 v = ((const f32x4*)inputs)[i];
  store4bf(r + (size_t)i * 4, f32x4{0.f, 0.f, 0.f, 0.f} - v);
}

extern "C" void kernel_launch(void* const* d_in, const int* in_sizes, int n_in,
                              void* d_out, int out_size, void* d_ws, size_t ws_size,
                              hipStream_t stream) {
  const float* inputs = (const float*)d_in[0];   // (BB, DD)
  const float* W      = (const float*)d_in[1];   // (KK, DD)
  const float* V      = (const float*)d_in[2];   // (CC, KK)
  const float* u0     = (const float*)d_in[3];   // (BB, CC)
  float* out = (float*)d_out;                    // (BB, DD)

  char* ws = (char*)d_ws;
  size_t off = 0;
  auto alloc = [&](size_t bytes) -> void* {
    void* p = ws + off;
    off += (bytes + 255) & ~(size_t)255;
    return p;
  };
  unsigned short* Wb = (unsigned short*)alloc((size_t)KK * DD * 2);  // W  (KK,DD)
  unsigned short* Wt = (unsigned short*)alloc((size_t)DD * KK * 2);  // W^T (DD,KK)
  unsigned short* Vb = (unsigned short*)alloc((size_t)CC * KK * 2);  // V  (CC,KK)
  unsigned short* Vt = (unsigned short*)alloc((size_t)KK * CC * 2);  // V^T (KK,CC)
  unsigned short* xb = (unsigned short*)alloc((size_t)BB * KK * 2);
  unsigned short* g  = (unsigned short*)alloc((size_t)BB * KK * 2);
  unsigned short* r  = (unsigned short*)alloc((size_t)BB * DD * 2);
  unsigned short* ub = (unsigned short*)alloc((size_t)BB * CC * 2);
  float* x    = (float*)alloc((size_t)BB * KK * 4);
  float* z    = (float*)alloc((size_t)BB * KK * 4);
  float* u    = (float*)alloc((size_t)BB * CC * 4);
  float* gxp  = (float*)alloc((size_t)2 * BB * KK * 4);  // 16 MB
  float* outp = (float*)alloc((size_t)4 * BB * DD * 4);  // 16 MB
  float* gup  = (float*)alloc((size_t)8 * BB * CC * 4);  // 8 MB

  convtrans_k<<<dim3(DD / 64, KK / 64), 256, 0, stream>>>(W, Wb, Wt, KK, DD);
  convtrans_k<<<dim3(KK / 64, CC / 64), 256, 0, stream>>>(V, Vb, Vt, CC, KK);
  zero_k<<<(BB * KK / 2 + 255) / 256, 256, 0, stream>>>((unsigned int*)xb, BB * KK / 2);
  zero_k<<<(BB * KK + 255) / 256, 256, 0, stream>>>((unsigned int*)x, BB * KK);
  initu_k<<<(BB * CC + 255) / 256, 256, 0, stream>>>(u0, u, ub, BB * CC);
  r0_k<<<BB * DD / 4 / 256, 256, 0, stream>>>(inputs, r);

  for (int t = 0; t < 9; t++) {
    // A: z_t (512 jobs x 8 iters) + gx-partials_t (1024 jobs x 16 iters)
    zgxp_k<<<1536, 256, 0, stream>>>(r, Wb, ub, Vt, gxp, z);
    // B: prox-x -> x_{t+1}, xb, g_t
    ep_x_k<<<BB * KK / 4 / 256, 256, 0, stream>>>(gxp, z, x, xb, g);
    if (t < 8) {
      // C: out-partials_{t+1} (1024 x 16) + gu-partials_t (512 x 8)
      cgo_k<<<1536, 256, 0, stream>>>(xb, Wt, g, Vb, outp, gup);
      // D: u-prox_t (256 blocks) + r_{t+1} (1024 blocks)
      ud_k<<<1280, 256, 0, stream>>>(gup, outp, inputs, u, ub, r);
    } else {
      // C: out-partials_9 only
      cgo_k<<<1024, 256, 0, stream>>>(xb, Wt, g, Vb, outp, gup);
      // D: final sum -> d_out
      ep_out_k<<<BB * DD / 4 / 256, 256, 0, stream>>>(outp, out);
    }
  }
}